// Round 1
// baseline (215.046 us; speedup 1.0000x reference)
//
#include <hip/hip_runtime.h>
#include <hip/hip_bf16.h>
#include <cstdint>

#define BM 128
#define BN 128
#define BK 64

typedef __bf16 bf16x8 __attribute__((ext_vector_type(8)));
typedef float f32x4 __attribute__((ext_vector_type(4)));

__device__ inline unsigned short f2bf(float f) {
  union { float f; unsigned u; } x; x.f = f;
  unsigned r = x.u + 0x7fffu + ((x.u >> 16) & 1u);
  return (unsigned short)(r >> 16);
}
__device__ inline float bf2f(unsigned short b) {
  union { unsigned u; float f; } x; x.u = ((unsigned)b) << 16;
  return x.f;
}

__device__ inline void gload_lds16(const void* g, void* l) {
  __builtin_amdgcn_global_load_lds(
      (const __attribute__((address_space(1))) unsigned int*)g,
      (__attribute__((address_space(3))) unsigned int*)l, 16, 0, 0);
}

// C = A * B^T (+bias) with A[M,K], B[N,K] row-major bf16 (ushort bits).
// MODE 0: C bf16 = acc + bias            (Q/K projection)
// MODE 1: C = V^T write: Vt[b][n][s] bf16 = acc + bias   (S=2048, N=1024 hardcoded)
// MODE 2: C bf16 = acc * scale, skip blocks fully above causal diagonal (scores)
// MODE 3: C fp32 = acc, K-loop bounded by causal row limit (PV)
template <int MODE>
__global__ __launch_bounds__(256) void gemm_bt(
    const unsigned short* __restrict__ A, int lda, long long sA,
    const unsigned short* __restrict__ B, int ldb, long long sB,
    void* __restrict__ C, int ldc, long long sC,
    const float* __restrict__ bias,
    int M, int N, int K, float scale)
{
  __shared__ unsigned short As[BM * BK];
  __shared__ unsigned short Bs[BN * BK];

  const int bx = blockIdx.x, by = blockIdx.y, bz = blockIdx.z;
  const int brow0 = bx * BM, bcol0 = by * BN;
  if (MODE == 2 && bcol0 > brow0 + (BM - 1)) return;  // fully above diagonal

  const unsigned short* Ab = A + (size_t)bz * sA;
  const unsigned short* Bb = B + (size_t)bz * sB;

  const int tid = threadIdx.x;
  const int wid = tid >> 6, lane = tid & 63;
  const int wr = wid >> 1, wc = wid & 1;

  f32x4 acc[4][4];
  #pragma unroll
  for (int i = 0; i < 4; ++i)
    #pragma unroll
    for (int j = 0; j < 4; ++j) acc[i][j] = (f32x4){0.f, 0.f, 0.f, 0.f};

  const int kend = (MODE == 3) ? min(K, (bx + 1) * BM) : K;

  const int frow = lane & 15;        // fragment row within 16
  const int fk   = (lane >> 4) * 8;  // k sub-offset within 32

  for (int k0 = 0; k0 < kend; k0 += BK) {
    // stage A,B tiles: linear LDS [128][64] bf16, global_load_lds width 16
    #pragma unroll
    for (int i = 0; i < 4; ++i) {
      const int e = (i * 256 + tid) * 8;
      const int r = e >> 6;         // /BK
      const int c = e & (BK - 1);
      gload_lds16(Ab + (size_t)(brow0 + r) * lda + k0 + c, &As[i * 2048 + wid * 512]);
      gload_lds16(Bb + (size_t)(bcol0 + r) * ldb + k0 + c, &Bs[i * 2048 + wid * 512]);
    }
    __syncthreads();
    #pragma unroll
    for (int kk = 0; kk < BK; kk += 32) {
      bf16x8 af[4], bfr[4];
      #pragma unroll
      for (int mi = 0; mi < 4; ++mi)
        af[mi] = *(const bf16x8*)&As[(wr * 64 + mi * 16 + frow) * BK + kk + fk];
      #pragma unroll
      for (int ni = 0; ni < 4; ++ni)
        bfr[ni] = *(const bf16x8*)&Bs[(wc * 64 + ni * 16 + frow) * BK + kk + fk];
      #pragma unroll
      for (int mi = 0; mi < 4; ++mi)
        #pragma unroll
        for (int ni = 0; ni < 4; ++ni)
          acc[mi][ni] = __builtin_amdgcn_mfma_f32_16x16x32_bf16(af[mi], bfr[ni], acc[mi][ni], 0, 0, 0);
    }
    __syncthreads();
  }

  // epilogue: C/D layout col=lane&15, row=(lane>>4)*4+reg (m89-verified)
  #pragma unroll
  for (int mi = 0; mi < 4; ++mi) {
    #pragma unroll
    for (int ni = 0; ni < 4; ++ni) {
      const int row0 = brow0 + wr * 64 + mi * 16 + (lane >> 4) * 4;
      const int col  = bcol0 + wc * 64 + ni * 16 + (lane & 15);
      if (MODE == 0) {
        const float bv = bias[col];
        unsigned short* Cb = (unsigned short*)C;
        #pragma unroll
        for (int r = 0; r < 4; ++r)
          Cb[(size_t)(row0 + r) * ldc + col] = f2bf(acc[mi][ni][r] + bv);
      } else if (MODE == 1) {
        const float bv = bias[col];
        unsigned short* Cb = (unsigned short*)C;
        const int bb = row0 >> 11, s0 = row0 & 2047;
        ushort4 pk;
        pk.x = f2bf(acc[mi][ni][0] + bv);
        pk.y = f2bf(acc[mi][ni][1] + bv);
        pk.z = f2bf(acc[mi][ni][2] + bv);
        pk.w = f2bf(acc[mi][ni][3] + bv);
        *(ushort4*)&Cb[(size_t)bb * (1024 * 2048) + (size_t)col * 2048 + s0] = pk;
      } else if (MODE == 2) {
        unsigned short* Cb = (unsigned short*)C + (size_t)bz * sC;
        #pragma unroll
        for (int r = 0; r < 4; ++r)
          Cb[(size_t)(row0 + r) * ldc + col] = f2bf(acc[mi][ni][r] * scale);
      } else {
        float* Cf = (float*)C + (size_t)bz * sC;
        #pragma unroll
        for (int r = 0; r < 4; ++r)
          Cf[(size_t)(row0 + r) * ldc + col] = acc[mi][ni][r];
      }
    }
  }
}

// in-place causal softmax on bf16 scores, one 256-thread block per row
__global__ __launch_bounds__(256) void softmax_causal(unsigned short* __restrict__ Sc) {
  const int row = blockIdx.x;     // b*2048 + i
  const int i = row & 2047;
  unsigned short* rp = Sc + (size_t)row * 2048;
  const int t = threadIdx.x;
  const int j0 = t * 8;

  uint4 raw = ((const uint4*)rp)[t];
  unsigned us[8];
  us[0] = raw.x & 0xffffu; us[1] = raw.x >> 16;
  us[2] = raw.y & 0xffffu; us[3] = raw.y >> 16;
  us[4] = raw.z & 0xffffu; us[5] = raw.z >> 16;
  us[6] = raw.w & 0xffffu; us[7] = raw.w >> 16;
  float v[8];
  #pragma unroll
  for (int e = 0; e < 8; ++e) v[e] = bf2f((unsigned short)us[e]);

  float m = -3.0e38f;
  #pragma unroll
  for (int e = 0; e < 8; ++e) if (j0 + e <= i) m = fmaxf(m, v[e]);
  #pragma unroll
  for (int o = 32; o > 0; o >>= 1) m = fmaxf(m, __shfl_xor(m, o));

  __shared__ float red[8];
  const int wid = t >> 6, lane = t & 63;
  if (lane == 0) red[wid] = m;
  __syncthreads();
  m = fmaxf(fmaxf(red[0], red[1]), fmaxf(red[2], red[3]));

  float ev[8];
  float s = 0.f;
  #pragma unroll
  for (int e = 0; e < 8; ++e) {
    float x = (j0 + e <= i) ? __expf(v[e] - m) : 0.f;
    ev[e] = x; s += x;
  }
  #pragma unroll
  for (int o = 32; o > 0; o >>= 1) s += __shfl_xor(s, o);
  if (lane == 0) red[4 + wid] = s;
  __syncthreads();
  s = red[4] + red[5] + red[6] + red[7];
  const float inv = 1.f / s;

  uint4 outw;
  outw.x = (unsigned)f2bf(ev[0] * inv) | ((unsigned)f2bf(ev[1] * inv) << 16);
  outw.y = (unsigned)f2bf(ev[2] * inv) | ((unsigned)f2bf(ev[3] * inv) << 16);
  outw.z = (unsigned)f2bf(ev[4] * inv) | ((unsigned)f2bf(ev[5] * inv) << 16);
  outw.w = (unsigned)f2bf(ev[6] * inv) | ((unsigned)f2bf(ev[7] * inv) << 16);
  ((uint4*)rp)[t] = outw;
}

__global__ __launch_bounds__(256) void cvt_f32_bf16(const float4* __restrict__ in,
                                                    ushort4* __restrict__ out, int n4) {
  const int idx = blockIdx.x * 256 + threadIdx.x;
  if (idx >= n4) return;
  float4 f = in[idx];
  ushort4 o;
  o.x = f2bf(f.x); o.y = f2bf(f.y); o.z = f2bf(f.z); o.w = f2bf(f.w);
  out[idx] = o;
}

extern "C" void kernel_launch(void* const* d_in, const int* in_sizes, int n_in,
                              void* d_out, int out_size, void* d_ws, size_t ws_size,
                              hipStream_t stream) {
  const float* x  = (const float*)d_in[0];
  const float* Wk = (const float*)d_in[1];
  const float* bk = (const float*)d_in[2];
  const float* Wq = (const float*)d_in[3];
  const float* bq = (const float*)d_in[4];
  const float* Wv = (const float*)d_in[5];
  const float* bv = (const float*)d_in[6];
  float* out = (float*)d_out;

  char* ws = (char*)d_ws;
  unsigned short* xb = (unsigned short*)(ws + 0);          // 8192x1024 bf16  (16 MB)
  unsigned short* Wb = (unsigned short*)(ws + 16777216);   // 3 x 1024x1024   (6 MB)
  unsigned short* Kb = (unsigned short*)(ws + 23068672);   // 8192x1024       (16 MB)
  unsigned short* Qb = (unsigned short*)(ws + 39845888);   // 8192x1024       (16 MB)
  unsigned short* Vt = (unsigned short*)(ws + 56623104);   // 4 x 1024x2048   (16 MB)
  unsigned short* Sc = (unsigned short*)(ws + 73400320);   // 4 x 2048x2048   (32 MB)

  // fp32 -> bf16 converts
  cvt_f32_bf16<<<8192, 256, 0, stream>>>((const float4*)x, (ushort4*)xb, 2097152);
  cvt_f32_bf16<<<1024, 256, 0, stream>>>((const float4*)Wk, (ushort4*)(Wb + 0), 262144);
  cvt_f32_bf16<<<1024, 256, 0, stream>>>((const float4*)Wq, (ushort4*)(Wb + 1048576), 262144);
  cvt_f32_bf16<<<1024, 256, 0, stream>>>((const float4*)Wv, (ushort4*)(Wb + 2097152), 262144);

  // projections: K, Q normal; V written transposed per batch
  gemm_bt<0><<<dim3(64, 8, 1), 256, 0, stream>>>(xb, 1024, 0, Wb + 0,       1024, 0, Kb, 1024, 0, bk, 8192, 1024, 1024, 1.f);
  gemm_bt<0><<<dim3(64, 8, 1), 256, 0, stream>>>(xb, 1024, 0, Wb + 1048576, 1024, 0, Qb, 1024, 0, bq, 8192, 1024, 1024, 1.f);
  gemm_bt<1><<<dim3(64, 8, 1), 256, 0, stream>>>(xb, 1024, 0, Wb + 2097152, 1024, 0, Vt, 1024, 0, bv, 8192, 1024, 1024, 1.f);

  // scores = Q K^T / 32 (bf16, lower-triangular blocks only)
  gemm_bt<2><<<dim3(16, 16, 4), 256, 0, stream>>>(Qb, 1024, 2048LL * 1024, Kb, 1024, 2048LL * 1024,
                                                  Sc, 2048, 2048LL * 2048, nullptr, 2048, 2048, 1024, 0.03125f);
  // in-place causal softmax -> P (bf16)
  softmax_causal<<<8192, 256, 0, stream>>>(Sc);
  // out = P @ V  (A=P bf16, B=Vt [1024][2048] bf16, causal k-bound)
  gemm_bt<3><<<dim3(16, 8, 4), 256, 0, stream>>>(Sc, 2048, 2048LL * 2048, Vt, 2048, 1024LL * 2048,
                                                 out, 1024, 2048LL * 1024, nullptr, 2048, 1024, 2048, 1.f);
}

// Round 2
// 181.816 us; speedup vs baseline: 1.1828x; 1.1828x over previous
//
#include <hip/hip_runtime.h>
#include <hip/hip_bf16.h>
#include <cstdint>

typedef __bf16 bf16x8 __attribute__((ext_vector_type(8)));
typedef float f32x4 __attribute__((ext_vector_type(4)));

#define SLOT_E 24576   // elems per LDS slot: A 256x64 (16384) + B 128x64 (8192)
#define A_E 16384
#define LDS_BYTES 147456  // 3 slots * 24576 * 2B

__device__ inline unsigned short f2bf(float f) {
  union { float f; unsigned u; } x; x.f = f;
  unsigned r = x.u + 0x7fffu + ((x.u >> 16) & 1u);
  return (unsigned short)(r >> 16);
}
__device__ inline float bf2f(unsigned short b) {
  union { unsigned u; float f; } x; x.u = ((unsigned)b) << 16;
  return x.f;
}

__device__ inline void gload_lds16(const void* g, void* l) {
  __builtin_amdgcn_global_load_lds(
      (const __attribute__((address_space(1))) unsigned int*)g,
      (__attribute__((address_space(3))) unsigned int*)l, 16, 0, 0);
}

// C = A * B^T (+bias). A[M,K], B[N,K] row-major bf16. BM=256, BN=128, BK=64.
// 8 waves (4M x 2N), per-wave 64x64 C. 3-slot LDS depth-2 pipeline, counted vmcnt,
// T2 XOR-swizzle (pre-swizzled global source + swizzled ds_read; LDS linear).
// MODE 0: fused QKV projection. by>>3 selects weight w: 0->K(C0), 1->Q(C1), 2->V transposed(C2).
// MODE 2: scores: C bf16 = acc*scale, skip blocks fully above causal diagonal.
// MODE 3: PV: C fp32 = acc, K bounded to (bx+1)*256.
template <int MODE>
__global__ __launch_bounds__(512) void gemm2(
    const unsigned short* __restrict__ A, int lda, long long sA,
    const unsigned short* __restrict__ B0, int ldb, long long sB,
    void* __restrict__ C0, int ldc, long long sC,
    const float* __restrict__ b0, const float* __restrict__ b1, const float* __restrict__ b2,
    void* __restrict__ C1, void* __restrict__ C2,
    int K, float scale)
{
  extern __shared__ unsigned short lds[];
  const int bx = blockIdx.x, by = blockIdx.y, bz = blockIdx.z;
  const int brow0 = bx * 256;
  int bcol0, w = 0;
  const unsigned short* Bp;
  if (MODE == 0) {
    w = by >> 3; bcol0 = (by & 7) * 128;
    Bp = B0 + (size_t)w * (1024 * 1024);
  } else {
    bcol0 = by * 128;
    Bp = B0 + (size_t)bz * sB;
    if (MODE == 2 && bcol0 > brow0 + 255) return;  // fully above diagonal
  }
  const unsigned short* Ap = A + (size_t)bz * sA;
  const int kend = (MODE == 3) ? min(K, brow0 + 256) : K;
  const int nt = kend >> 6;

  const int tid = threadIdx.x;
  const int wid = tid >> 6, lane = tid & 63;
  const int wr = wid >> 1, wc = wid & 1;
  const int frow = lane & 15, fk = (lane >> 4) * 8;

  // precomputed swizzled ds_read elem indices (constant per thread)
  int idxA[2][4], idxB[2][4];
  #pragma unroll
  for (int kk = 0; kk < 2; ++kk) {
    #pragma unroll
    for (int i = 0; i < 4; ++i) {
      const int ar = wr * 64 + i * 16 + frow;
      idxA[kk][i] = (ar * 64 + kk * 32 + fk) ^ ((ar & 7) << 3);
      const int br = wc * 64 + i * 16 + frow;
      idxB[kk][i] = A_E + ((br * 64 + kk * 32 + fk) ^ ((br & 7) << 3));
    }
  }

  f32x4 acc[4][4];
  #pragma unroll
  for (int i = 0; i < 4; ++i)
    #pragma unroll
    for (int j = 0; j < 4; ++j) acc[i][j] = (f32x4){0.f, 0.f, 0.f, 0.f};

  // staging: LDS linear dest; source column pre-swizzled (rule 21: both-sides)
  auto stage = [&](int t, int slot) {
    const int k0 = t << 6;
    unsigned short* sb = &lds[slot * SLOT_E];
    #pragma unroll
    for (int i = 0; i < 4; ++i) {
      const int e = (i * 512 + tid) * 8;
      const int r = e >> 6, c = e & 63;
      gload_lds16(Ap + (size_t)(brow0 + r) * lda + (k0 + (c ^ ((r & 7) << 3))), &sb[e]);
    }
    #pragma unroll
    for (int i = 0; i < 2; ++i) {
      const int e = (i * 512 + tid) * 8;
      const int r = e >> 6, c = e & 63;
      gload_lds16(Bp + (size_t)(bcol0 + r) * ldb + (k0 + (c ^ ((r & 7) << 3))), &sb[A_E + e]);
    }
  };

  stage(0, 0);
  stage(1, 1);
  int slot = 0;
  for (int t = 0; t < nt; ++t) {
    if (t + 2 < nt) {
      stage(t + 2, (slot + 2 >= 3) ? slot - 1 : slot + 2);
      asm volatile("s_waitcnt vmcnt(12)" ::: "memory");   // tiles t+1,t+2 in flight
    } else if (t + 1 < nt) {
      asm volatile("s_waitcnt vmcnt(6)" ::: "memory");    // tile t+1 in flight
    } else {
      asm volatile("s_waitcnt vmcnt(0)" ::: "memory");    // drain (also before endpgm)
    }
    __builtin_amdgcn_s_barrier();
    const unsigned short* sb = &lds[slot * SLOT_E];
    #pragma unroll
    for (int kk = 0; kk < 2; ++kk) {
      bf16x8 af[4], bf[4];
      #pragma unroll
      for (int i = 0; i < 4; ++i) af[i] = *(const bf16x8*)&sb[idxA[kk][i]];
      #pragma unroll
      for (int i = 0; i < 4; ++i) bf[i] = *(const bf16x8*)&sb[idxB[kk][i]];
      __builtin_amdgcn_s_setprio(1);
      #pragma unroll
      for (int mi = 0; mi < 4; ++mi)
        #pragma unroll
        for (int ni = 0; ni < 4; ++ni)
          acc[mi][ni] = __builtin_amdgcn_mfma_f32_16x16x32_bf16(af[mi], bf[ni], acc[mi][ni], 0, 0, 0);
      __builtin_amdgcn_s_setprio(0);
    }
    __builtin_amdgcn_s_barrier();
    slot = (slot == 2) ? 0 : slot + 1;
  }

  // epilogue: C/D layout col=lane&15, row=(lane>>4)*4+reg
  const float* bias = nullptr;
  if (MODE == 0) bias = (w == 0) ? b0 : (w == 1) ? b1 : b2;

  #pragma unroll
  for (int mi = 0; mi < 4; ++mi) {
    #pragma unroll
    for (int ni = 0; ni < 4; ++ni) {
      const int row0 = brow0 + wr * 64 + mi * 16 + (lane >> 4) * 4;
      const int col = bcol0 + wc * 64 + ni * 16 + frow;
      if (MODE == 0) {
        const float bv = bias[col];
        if (w == 2) {
          unsigned short* Cb = (unsigned short*)C2;
          const int bb = row0 >> 11, s0 = row0 & 2047;
          ushort4 pk;
          pk.x = f2bf(acc[mi][ni][0] + bv);
          pk.y = f2bf(acc[mi][ni][1] + bv);
          pk.z = f2bf(acc[mi][ni][2] + bv);
          pk.w = f2bf(acc[mi][ni][3] + bv);
          *(ushort4*)&Cb[(size_t)bb * (1024 * 2048) + (size_t)col * 2048 + s0] = pk;
        } else {
          unsigned short* Cb = (unsigned short*)(w == 0 ? C0 : C1);
          #pragma unroll
          for (int r = 0; r < 4; ++r)
            Cb[(size_t)(row0 + r) * ldc + col] = f2bf(acc[mi][ni][r] + bv);
        }
      } else if (MODE == 2) {
        unsigned short* Cb = (unsigned short*)C0 + (size_t)bz * sC;
        #pragma unroll
        for (int r = 0; r < 4; ++r)
          Cb[(size_t)(row0 + r) * ldc + col] = f2bf(acc[mi][ni][r] * scale);
      } else {
        float* Cf = (float*)C0 + (size_t)bz * sC;
        #pragma unroll
        for (int r = 0; r < 4; ++r)
          Cf[(size_t)(row0 + r) * ldc + col] = acc[mi][ni][r];
      }
    }
  }
}

// in-place causal softmax on bf16 scores, one 256-thread block per row
__global__ __launch_bounds__(256) void softmax_causal(unsigned short* __restrict__ Sc) {
  const int row = blockIdx.x;     // b*2048 + i
  const int i = row & 2047;
  unsigned short* rp = Sc + (size_t)row * 2048;
  const int t = threadIdx.x;
  const int j0 = t * 8;

  uint4 raw = ((const uint4*)rp)[t];
  unsigned us[8];
  us[0] = raw.x & 0xffffu; us[1] = raw.x >> 16;
  us[2] = raw.y & 0xffffu; us[3] = raw.y >> 16;
  us[4] = raw.z & 0xffffu; us[5] = raw.z >> 16;
  us[6] = raw.w & 0xffffu; us[7] = raw.w >> 16;
  float v[8];
  #pragma unroll
  for (int e = 0; e < 8; ++e) v[e] = bf2f((unsigned short)us[e]);

  float m = -3.0e38f;
  #pragma unroll
  for (int e = 0; e < 8; ++e) if (j0 + e <= i) m = fmaxf(m, v[e]);
  #pragma unroll
  for (int o = 32; o > 0; o >>= 1) m = fmaxf(m, __shfl_xor(m, o));

  __shared__ float red[8];
  const int wid = t >> 6, lane = t & 63;
  if (lane == 0) red[wid] = m;
  __syncthreads();
  m = fmaxf(fmaxf(red[0], red[1]), fmaxf(red[2], red[3]));

  float ev[8];
  float s = 0.f;
  #pragma unroll
  for (int e = 0; e < 8; ++e) {
    float x = (j0 + e <= i) ? __expf(v[e] - m) : 0.f;
    ev[e] = x; s += x;
  }
  #pragma unroll
  for (int o = 32; o > 0; o >>= 1) s += __shfl_xor(s, o);
  if (lane == 0) red[4 + wid] = s;
  __syncthreads();
  s = red[4] + red[5] + red[6] + red[7];
  const float inv = 1.f / s;

  uint4 outw;
  outw.x = (unsigned)f2bf(ev[0] * inv) | ((unsigned)f2bf(ev[1] * inv) << 16);
  outw.y = (unsigned)f2bf(ev[2] * inv) | ((unsigned)f2bf(ev[3] * inv) << 16);
  outw.z = (unsigned)f2bf(ev[4] * inv) | ((unsigned)f2bf(ev[5] * inv) << 16);
  outw.w = (unsigned)f2bf(ev[6] * inv) | ((unsigned)f2bf(ev[7] * inv) << 16);
  ((uint4*)rp)[t] = outw;
}

__global__ __launch_bounds__(256) void cvt_f32_bf16(const float4* __restrict__ in,
                                                    ushort4* __restrict__ out, int n4) {
  const int idx = blockIdx.x * 256 + threadIdx.x;
  if (idx >= n4) return;
  float4 f = in[idx];
  ushort4 o;
  o.x = f2bf(f.x); o.y = f2bf(f.y); o.z = f2bf(f.z); o.w = f2bf(f.w);
  out[idx] = o;
}

extern "C" void kernel_launch(void* const* d_in, const int* in_sizes, int n_in,
                              void* d_out, int out_size, void* d_ws, size_t ws_size,
                              hipStream_t stream) {
  const float* x  = (const float*)d_in[0];
  const float* Wk = (const float*)d_in[1];
  const float* bk = (const float*)d_in[2];
  const float* Wq = (const float*)d_in[3];
  const float* bq = (const float*)d_in[4];
  const float* Wv = (const float*)d_in[5];
  const float* bv = (const float*)d_in[6];
  float* out = (float*)d_out;

  char* ws = (char*)d_ws;
  unsigned short* xb = (unsigned short*)(ws + 0);          // 8192x1024 bf16  (16 MB)
  unsigned short* Wb = (unsigned short*)(ws + 16777216);   // 3 x 1024x1024   (6 MB)
  unsigned short* Kb = (unsigned short*)(ws + 23068672);   // 8192x1024       (16 MB)
  unsigned short* Qb = (unsigned short*)(ws + 39845888);   // 8192x1024       (16 MB)
  unsigned short* Vt = (unsigned short*)(ws + 56623104);   // 4 x 1024x2048   (16 MB)
  unsigned short* Sc = (unsigned short*)(ws + 73400320);   // 4 x 2048x2048   (32 MB)

  // opt-in for 144 KB dynamic LDS (idempotent, capture-safe)
  (void)hipFuncSetAttribute(reinterpret_cast<const void*>(&gemm2<0>),
                            hipFuncAttributeMaxDynamicSharedMemorySize, LDS_BYTES);
  (void)hipFuncSetAttribute(reinterpret_cast<const void*>(&gemm2<2>),
                            hipFuncAttributeMaxDynamicSharedMemorySize, LDS_BYTES);
  (void)hipFuncSetAttribute(reinterpret_cast<const void*>(&gemm2<3>),
                            hipFuncAttributeMaxDynamicSharedMemorySize, LDS_BYTES);

  // fp32 -> bf16 converts
  cvt_f32_bf16<<<8192, 256, 0, stream>>>((const float4*)x, (ushort4*)xb, 2097152);
  cvt_f32_bf16<<<1024, 256, 0, stream>>>((const float4*)Wk, (ushort4*)(Wb + 0), 262144);
  cvt_f32_bf16<<<1024, 256, 0, stream>>>((const float4*)Wq, (ushort4*)(Wb + 1048576), 262144);
  cvt_f32_bf16<<<1024, 256, 0, stream>>>((const float4*)Wv, (ushort4*)(Wb + 2097152), 262144);

  // fused QKV projections: by>>3 = weight {K,Q,V}; V written transposed
  gemm2<0><<<dim3(32, 24, 1), 512, LDS_BYTES, stream>>>(
      xb, 1024, 0, Wb, 1024, 0, Kb, 1024, 0, bk, bq, bv, Qb, Vt, 1024, 1.f);

  // scores = Q K^T / 32 (bf16, causal blocks only)
  gemm2<2><<<dim3(8, 16, 4), 512, LDS_BYTES, stream>>>(
      Qb, 1024, 2048LL * 1024, Kb, 1024, 2048LL * 1024,
      Sc, 2048, 2048LL * 2048, nullptr, nullptr, nullptr, nullptr, nullptr, 1024, 0.03125f);

  // in-place causal softmax -> P (bf16)
  softmax_causal<<<8192, 256, 0, stream>>>(Sc);

  // out = P @ V  (A=P bf16, B=Vt [1024][2048] bf16, causal k-bound)
  gemm2<3><<<dim3(8, 8, 4), 512, LDS_BYTES, stream>>>(
      Sc, 2048, 2048LL * 2048, Vt, 2048, 1024LL * 2048,
      out, 1024, 2048LL * 1024, nullptr, nullptr, nullptr, nullptr, nullptr, 2048, 1.f);
}

// Round 3
// 164.705 us; speedup vs baseline: 1.3056x; 1.1039x over previous
//
#include <hip/hip_runtime.h>
#include <hip/hip_bf16.h>
#include <cstdint>

typedef __bf16 bf16x8 __attribute__((ext_vector_type(8)));
typedef float f32x4 __attribute__((ext_vector_type(4)));

#define SLOT_E 24576   // elems per LDS slot: A 256x64 (16384) + B 128x64 (8192)
#define A_E 16384
#define LDS_BYTES 147456  // 3 slots * 24576 * 2B

__device__ inline unsigned short f2bf(float f) {
  union { float f; unsigned u; } x; x.f = f;
  unsigned r = x.u + 0x7fffu + ((x.u >> 16) & 1u);
  return (unsigned short)(r >> 16);
}
__device__ inline float bf2f(unsigned short b) {
  union { unsigned u; float f; } x; x.u = ((unsigned)b) << 16;
  return x.f;
}

__device__ inline void gload_lds16(const void* g, void* l) {
  __builtin_amdgcn_global_load_lds(
      (const __attribute__((address_space(1))) unsigned int*)g,
      (__attribute__((address_space(3))) unsigned int*)l, 16, 0, 0);
}

// C = A * B^T (+bias). A[M,K], B[N,K] row-major bf16. BM=256, BN=128, BK=64.
// 8 waves (4M x 2N), per-wave 64x64 C. 3-slot LDS depth-2 pipeline, counted vmcnt,
// T2 XOR-swizzle, T3 2-fine-phases per K-step (8 ds_read + 3 stage + barrier +
// 16-MFMA setprio cluster each), T5 setprio.
// MODE 0: fused QKV projection. by>>3 selects weight w: 0->K(C0), 1->Q(C1), 2->V transposed(C2).
// MODE 2: scores: C bf16 = acc*scale, skip blocks fully above causal diagonal.
// MODE 3: PV: C fp32 = acc, K bounded to (bx+1)*256.
template <int MODE>
__global__ __launch_bounds__(512) void gemm2(
    const unsigned short* __restrict__ A, int lda, long long sA,
    const unsigned short* __restrict__ B0, int ldb, long long sB,
    void* __restrict__ C0, int ldc, long long sC,
    const float* __restrict__ b0, const float* __restrict__ b1, const float* __restrict__ b2,
    void* __restrict__ C1, void* __restrict__ C2,
    int K, float scale)
{
  extern __shared__ unsigned short lds[];
  const int bx = blockIdx.x, by = blockIdx.y, bz = blockIdx.z;
  const int brow0 = bx * 256;
  int bcol0, w = 0;
  const unsigned short* Bp;
  if (MODE == 0) {
    w = by >> 3; bcol0 = (by & 7) * 128;
    Bp = B0 + (size_t)w * (1024 * 1024);
  } else {
    bcol0 = by * 128;
    Bp = B0 + (size_t)bz * sB;
    if (MODE == 2 && bcol0 > brow0 + 255) return;  // fully above diagonal
  }
  const unsigned short* Ap = A + (size_t)bz * sA;
  const int kend = (MODE == 3) ? min(K, brow0 + 256) : K;
  const int nt = kend >> 6;

  const int tid = threadIdx.x;
  const int wid = tid >> 6, lane = tid & 63;
  const int wr = wid >> 1, wc = wid & 1;
  const int frow = lane & 15, fk = (lane >> 4) * 8;

  // precomputed swizzled ds_read elem indices (constant per thread)
  int idxA[2][4], idxB[2][4];
  #pragma unroll
  for (int kk = 0; kk < 2; ++kk) {
    #pragma unroll
    for (int i = 0; i < 4; ++i) {
      const int ar = wr * 64 + i * 16 + frow;
      idxA[kk][i] = (ar * 64 + kk * 32 + fk) ^ ((ar & 7) << 3);
      const int br = wc * 64 + i * 16 + frow;
      idxB[kk][i] = A_E + ((br * 64 + kk * 32 + fk) ^ ((br & 7) << 3));
    }
  }

  f32x4 acc[4][4];
  #pragma unroll
  for (int i = 0; i < 4; ++i)
    #pragma unroll
    for (int j = 0; j < 4; ++j) acc[i][j] = (f32x4){0.f, 0.f, 0.f, 0.f};

  // staging pieces: LDS linear dest; source column pre-swizzled (both-sides rule)
  auto stA = [&](unsigned short* sb, int k0, int i) {
    const int e = (i * 512 + tid) * 8;
    const int r = e >> 6, c = e & 63;
    gload_lds16(Ap + (size_t)(brow0 + r) * lda + (k0 + (c ^ ((r & 7) << 3))), &sb[e]);
  };
  auto stB = [&](unsigned short* sb, int k0, int i) {
    const int e = (i * 512 + tid) * 8;
    const int r = e >> 6, c = e & 63;
    gload_lds16(Bp + (size_t)(bcol0 + r) * ldb + (k0 + (c ^ ((r & 7) << 3))), &sb[A_E + e]);
  };

  // prologue: stage tiles 0,1; wait tile 0 (leave tile 1's 6 loads in flight)
  {
    unsigned short* s0 = &lds[0];
    #pragma unroll
    for (int i = 0; i < 4; ++i) stA(s0, 0, i);
    #pragma unroll
    for (int i = 0; i < 2; ++i) stB(s0, 0, i);
    unsigned short* s1 = &lds[SLOT_E];
    #pragma unroll
    for (int i = 0; i < 4; ++i) stA(s1, 64, i);
    #pragma unroll
    for (int i = 0; i < 2; ++i) stB(s1, 64, i);
  }
  asm volatile("s_waitcnt vmcnt(6)" ::: "memory");
  __builtin_amdgcn_s_barrier();

  int slot = 0;
  for (int t = 0; t < nt; ++t) {
    const unsigned short* sb = &lds[slot * SLOT_E];
    const int s2 = (slot + 2 >= 3) ? slot - 1 : slot + 2;
    unsigned short* sb2 = &lds[s2 * SLOT_E];
    const bool pf = (t + 2 < nt);
    const int k2 = (t + 2) << 6;

    // ---- phase 0: kk=0 subtile ∥ 3 stage loads ∥ barrier ∥ 16 MFMA ----
    bf16x8 a0[4], b0f[4];
    #pragma unroll
    for (int i = 0; i < 4; ++i) a0[i] = *(const bf16x8*)&sb[idxA[0][i]];
    #pragma unroll
    for (int i = 0; i < 4; ++i) b0f[i] = *(const bf16x8*)&sb[idxB[0][i]];
    if (pf) {
      stA(sb2, k2, 0); stA(sb2, k2, 1); stA(sb2, k2, 2);
    }
    __builtin_amdgcn_s_barrier();
    __builtin_amdgcn_s_setprio(1);
    #pragma unroll
    for (int mi = 0; mi < 4; ++mi)
      #pragma unroll
      for (int ni = 0; ni < 4; ++ni)
        acc[mi][ni] = __builtin_amdgcn_mfma_f32_16x16x32_bf16(a0[mi], b0f[ni], acc[mi][ni], 0, 0, 0);
    __builtin_amdgcn_s_setprio(0);

    // ---- phase 1: kk=1 subtile ∥ 3 stage loads ∥ vmcnt ∥ barrier ∥ 16 MFMA ----
    bf16x8 a1[4], b1f[4];
    #pragma unroll
    for (int i = 0; i < 4; ++i) a1[i] = *(const bf16x8*)&sb[idxA[1][i]];
    #pragma unroll
    for (int i = 0; i < 4; ++i) b1f[i] = *(const bf16x8*)&sb[idxB[1][i]];
    if (pf) {
      stA(sb2, k2, 3); stB(sb2, k2, 0); stB(sb2, k2, 1);
      asm volatile("s_waitcnt vmcnt(6)" ::: "memory");   // tile t+1 ready; t+2 in flight
    } else {
      asm volatile("s_waitcnt vmcnt(0)" ::: "memory");   // drain tail
    }
    __builtin_amdgcn_s_barrier();
    __builtin_amdgcn_s_setprio(1);
    #pragma unroll
    for (int mi = 0; mi < 4; ++mi)
      #pragma unroll
      for (int ni = 0; ni < 4; ++ni)
        acc[mi][ni] = __builtin_amdgcn_mfma_f32_16x16x32_bf16(a1[mi], b1f[ni], acc[mi][ni], 0, 0, 0);
    __builtin_amdgcn_s_setprio(0);
    __builtin_amdgcn_s_barrier();   // slot-lifecycle barrier (reads done before restage)

    slot = (slot == 2) ? 0 : slot + 1;
  }

  // epilogue: C/D layout col=lane&15, row=(lane>>4)*4+reg
  const float* bias = nullptr;
  if (MODE == 0) bias = (w == 0) ? b0 : (w == 1) ? b1 : b2;

  #pragma unroll
  for (int mi = 0; mi < 4; ++mi) {
    #pragma unroll
    for (int ni = 0; ni < 4; ++ni) {
      const int row0 = brow0 + wr * 64 + mi * 16 + (lane >> 4) * 4;
      const int col = bcol0 + wc * 64 + ni * 16 + frow;
      if (MODE == 0) {
        const float bv = bias[col];
        if (w == 2) {
          unsigned short* Cb = (unsigned short*)C2;
          const int bb = row0 >> 11, s0 = row0 & 2047;
          ushort4 pk;
          pk.x = f2bf(acc[mi][ni][0] + bv);
          pk.y = f2bf(acc[mi][ni][1] + bv);
          pk.z = f2bf(acc[mi][ni][2] + bv);
          pk.w = f2bf(acc[mi][ni][3] + bv);
          *(ushort4*)&Cb[(size_t)bb * (1024 * 2048) + (size_t)col * 2048 + s0] = pk;
        } else {
          unsigned short* Cb = (unsigned short*)(w == 0 ? C0 : C1);
          #pragma unroll
          for (int r = 0; r < 4; ++r)
            Cb[(size_t)(row0 + r) * ldc + col] = f2bf(acc[mi][ni][r] + bv);
        }
      } else if (MODE == 2) {
        unsigned short* Cb = (unsigned short*)C0 + (size_t)bz * sC;
        #pragma unroll
        for (int r = 0; r < 4; ++r)
          Cb[(size_t)(row0 + r) * ldc + col] = f2bf(acc[mi][ni][r] * scale);
      } else {
        float* Cf = (float*)C0 + (size_t)bz * sC;
        #pragma unroll
        for (int r = 0; r < 4; ++r)
          Cf[(size_t)(row0 + r) * ldc + col] = acc[mi][ni][r];
      }
    }
  }
}

// in-place causal softmax on bf16 scores, one 256-thread block per row
__global__ __launch_bounds__(256) void softmax_causal(unsigned short* __restrict__ Sc) {
  const int row = blockIdx.x;     // b*2048 + i
  const int i = row & 2047;
  unsigned short* rp = Sc + (size_t)row * 2048;
  const int t = threadIdx.x;
  const int j0 = t * 8;

  uint4 raw = ((const uint4*)rp)[t];
  unsigned us[8];
  us[0] = raw.x & 0xffffu; us[1] = raw.x >> 16;
  us[2] = raw.y & 0xffffu; us[3] = raw.y >> 16;
  us[4] = raw.z & 0xffffu; us[5] = raw.z >> 16;
  us[6] = raw.w & 0xffffu; us[7] = raw.w >> 16;
  float v[8];
  #pragma unroll
  for (int e = 0; e < 8; ++e) v[e] = bf2f((unsigned short)us[e]);

  float m = -3.0e38f;
  #pragma unroll
  for (int e = 0; e < 8; ++e) if (j0 + e <= i) m = fmaxf(m, v[e]);
  #pragma unroll
  for (int o = 32; o > 0; o >>= 1) m = fmaxf(m, __shfl_xor(m, o));

  __shared__ float red[8];
  const int wid = t >> 6, lane = t & 63;
  if (lane == 0) red[wid] = m;
  __syncthreads();
  m = fmaxf(fmaxf(red[0], red[1]), fmaxf(red[2], red[3]));

  float ev[8];
  float s = 0.f;
  #pragma unroll
  for (int e = 0; e < 8; ++e) {
    float x = (j0 + e <= i) ? __expf(v[e] - m) : 0.f;
    ev[e] = x; s += x;
  }
  #pragma unroll
  for (int o = 32; o > 0; o >>= 1) s += __shfl_xor(s, o);
  if (lane == 0) red[4 + wid] = s;
  __syncthreads();
  s = red[4] + red[5] + red[6] + red[7];
  const float inv = 1.f / s;

  uint4 outw;
  outw.x = (unsigned)f2bf(ev[0] * inv) | ((unsigned)f2bf(ev[1] * inv) << 16);
  outw.y = (unsigned)f2bf(ev[2] * inv) | ((unsigned)f2bf(ev[3] * inv) << 16);
  outw.z = (unsigned)f2bf(ev[4] * inv) | ((unsigned)f2bf(ev[5] * inv) << 16);
  outw.w = (unsigned)f2bf(ev[6] * inv) | ((unsigned)f2bf(ev[7] * inv) << 16);
  ((uint4*)rp)[t] = outw;
}

__global__ __launch_bounds__(256) void cvt_f32_bf16(const float4* __restrict__ in,
                                                    ushort4* __restrict__ out, int n4) {
  const int idx = blockIdx.x * 256 + threadIdx.x;
  if (idx >= n4) return;
  float4 f = in[idx];
  ushort4 o;
  o.x = f2bf(f.x); o.y = f2bf(f.y); o.z = f2bf(f.z); o.w = f2bf(f.w);
  out[idx] = o;
}

// convert the three 1024x1024 weights in one launch: 3072 blocks
__global__ __launch_bounds__(256) void cvt_w3(const float4* __restrict__ w0,
                                              const float4* __restrict__ w1,
                                              const float4* __restrict__ w2,
                                              ushort4* __restrict__ out) {
  const int g = blockIdx.x;            // [0,3072)
  const int sel = g >> 10;             // 1024 blocks per weight
  const int idx = (g & 1023) * 256 + threadIdx.x;   // [0, 262144)
  const float4* in = (sel == 0) ? w0 : (sel == 1) ? w1 : w2;
  float4 f = in[idx];
  ushort4 o;
  o.x = f2bf(f.x); o.y = f2bf(f.y); o.z = f2bf(f.z); o.w = f2bf(f.w);
  out[(size_t)sel * 262144 + idx] = o;
}

extern "C" void kernel_launch(void* const* d_in, const int* in_sizes, int n_in,
                              void* d_out, int out_size, void* d_ws, size_t ws_size,
                              hipStream_t stream) {
  const float* x  = (const float*)d_in[0];
  const float* Wk = (const float*)d_in[1];
  const float* bk = (const float*)d_in[2];
  const float* Wq = (const float*)d_in[3];
  const float* bq = (const float*)d_in[4];
  const float* Wv = (const float*)d_in[5];
  const float* bv = (const float*)d_in[6];
  float* out = (float*)d_out;

  char* ws = (char*)d_ws;
  unsigned short* xb = (unsigned short*)(ws + 0);          // 8192x1024 bf16  (16 MB)
  unsigned short* Wb = (unsigned short*)(ws + 16777216);   // 3 x 1024x1024   (6 MB)
  unsigned short* Kb = (unsigned short*)(ws + 23068672);   // 8192x1024       (16 MB)
  unsigned short* Qb = (unsigned short*)(ws + 39845888);   // 8192x1024       (16 MB)
  unsigned short* Vt = (unsigned short*)(ws + 56623104);   // 4 x 1024x2048   (16 MB)
  unsigned short* Sc = (unsigned short*)(ws + 73400320);   // 4 x 2048x2048   (32 MB)

  // opt-in for 144 KB dynamic LDS (idempotent, capture-safe)
  (void)hipFuncSetAttribute(reinterpret_cast<const void*>(&gemm2<0>),
                            hipFuncAttributeMaxDynamicSharedMemorySize, LDS_BYTES);
  (void)hipFuncSetAttribute(reinterpret_cast<const void*>(&gemm2<2>),
                            hipFuncAttributeMaxDynamicSharedMemorySize, LDS_BYTES);
  (void)hipFuncSetAttribute(reinterpret_cast<const void*>(&gemm2<3>),
                            hipFuncAttributeMaxDynamicSharedMemorySize, LDS_BYTES);

  // fp32 -> bf16 converts
  cvt_f32_bf16<<<8192, 256, 0, stream>>>((const float4*)x, (ushort4*)xb, 2097152);
  cvt_w3<<<3072, 256, 0, stream>>>((const float4*)Wk, (const float4*)Wq, (const float4*)Wv,
                                   (ushort4*)Wb);

  // fused QKV projections: by>>3 = weight {K,Q,V}; V written transposed
  // (Wb order now: 0=Wk, 1=Wq, 2=Wv)
  gemm2<0><<<dim3(32, 24, 1), 512, LDS_BYTES, stream>>>(
      xb, 1024, 0, Wb, 1024, 0, Kb, 1024, 0, bk, bq, bv, Qb, Vt, 1024, 1.f);

  // scores = Q K^T / 32 (bf16, causal blocks only)
  gemm2<2><<<dim3(8, 16, 4), 512, LDS_BYTES, stream>>>(
      Qb, 1024, 2048LL * 1024, Kb, 1024, 2048LL * 1024,
      Sc, 2048, 2048LL * 2048, nullptr, nullptr, nullptr, nullptr, nullptr, 1024, 0.03125f);

  // in-place causal softmax -> P (bf16)
  softmax_causal<<<8192, 256, 0, stream>>>(Sc);

  // out = P @ V  (A=P bf16, B=Vt [1024][2048] bf16, causal k-bound)
  gemm2<3><<<dim3(8, 8, 4), 512, LDS_BYTES, stream>>>(
      Sc, 2048, 2048LL * 2048, Vt, 2048, 1024LL * 2048,
      out, 1024, 2048LL * 1024, nullptr, nullptr, nullptr, nullptr, nullptr, 2048, 1.f);
}